// Round 13
// baseline (391.297 us; speedup 1.0000x reference)
//
#include <hip/hip_runtime.h>
#include <hip/hip_fp16.h>

#define BLK 256
#define BBLK 512             // k_bin block
#define ABLK 512             // agg1 block: 256 lane-pairs
#define DBLK 512             // ldeg_t1 / agg2 block (dual LDS accumulators)
#define NBK 782              // dst buckets of 256 nodes (782*256 >= 200000)
#define BW 256               // nodes per bucket (dl fits 8 bits)
#define CAP 6656             // edges counting-sorted per chunk in agg1 (26.6 KB -> 4 blk/CU)
#define CHUNK 4096           // edges per binning block -> 1563 blocks, 36 KB LDS (4/CU)

// ---------- bucket build ----------

__global__ void k_zero_i(int* __restrict__ p, int n) {
  int i = blockIdx.x * blockDim.x + threadIdx.x;
  if (i < n) p[i] = 0;
}

// per-block histogram -> blockhist row (persisted) + global bucket counts
__global__ void k_hist(const int* __restrict__ dst, int e, int* __restrict__ gcnt,
                       int* __restrict__ blockhist) {
  __shared__ int h[NBK];
  for (int i = threadIdx.x; i < NBK; i += BLK) h[i] = 0;
  __syncthreads();
  int base = blockIdx.x * CHUNK;
  int m = min(CHUNK, e - base);
  for (int k = threadIdx.x; k < m; k += BLK) atomicAdd(&h[dst[base + k] >> 8], 1);
  __syncthreads();
  int* row = blockhist + (size_t)blockIdx.x * NBK;
  for (int b = threadIdx.x; b < NBK; b += BLK) {
    int c = h[b];
    row[b] = c;
    if (c) atomicAdd(&gcnt[b], c);
  }
}

// exclusive scan of gcnt[NBK] -> gbase[NBK+1]; init gcur. single block, 1024 thr.
__global__ void k_scan(const int* __restrict__ gcnt, int* __restrict__ gbase,
                       int* __restrict__ gcur, int e) {
  __shared__ int s[1024];
  int t = threadIdx.x;
  int v = (t < NBK) ? gcnt[t] : 0;
  s[t] = v;
  __syncthreads();
  for (int d = 1; d < 1024; d <<= 1) {
    int u = (t >= d) ? s[t - d] : 0;
    __syncthreads();
    s[t] += u;
    __syncthreads();
  }
  if (t < NBK) { int ex = s[t] - v; gbase[t] = ex; gcur[t] = ex; }
  if (t == 0) gbase[NBK] = e;
}

// bin edges: load saved histogram, LDS counting-sort, coalesced write-out with
// direct pos->bucket lookup.
__global__ void __launch_bounds__(BBLK) k_bin(const int* __restrict__ src,
                                              const int* __restrict__ dst, int e,
                                              int* __restrict__ gcur,
                                              const int* __restrict__ blockhist,
                                              unsigned* __restrict__ binned) {
  __shared__ int lcnt[NBK];        // histogram, then reused as scatter cursor
  __shared__ int loff[NBK + 1];
  __shared__ int lbase[NBK];
  __shared__ int part[BBLK];
  __shared__ unsigned sorted[CHUNK];        // 16 KB
  __shared__ unsigned short bkt16[CHUNK];   // 8 KB
  int t = threadIdx.x;
  int base = blockIdx.x * CHUNK;
  int m = min(CHUNK, e - base);

  const int* row = blockhist + (size_t)blockIdx.x * NBK;
  for (int i = t; i < NBK; i += BBLK) lcnt[i] = row[i];
  __syncthreads();
  // exclusive scan over 782 bins (2 bins/thread + Hillis-Steele over 512 partials)
  int b0 = 2 * t;
  int s0 = (b0 + 0 < NBK) ? lcnt[b0 + 0] : 0;
  int s1 = (b0 + 1 < NBK) ? lcnt[b0 + 1] : 0;
  int tsum = s0 + s1;
  part[t] = tsum;
  __syncthreads();
  for (int d = 1; d < BBLK; d <<= 1) {
    int u = (t >= d) ? part[t - d] : 0;
    __syncthreads();
    part[t] += u;
    __syncthreads();
  }
  int ex = part[t] - tsum;
  if (b0 + 0 < NBK) loff[b0 + 0] = ex;
  if (b0 + 1 < NBK) loff[b0 + 1] = ex + s0;
  if (t == 0) loff[NBK] = m;
  __syncthreads();
  for (int b = t; b < NBK; b += BBLK) {
    int c = lcnt[b];
    lbase[b] = c ? atomicAdd(&gcur[b], c) : 0;
  }
  __syncthreads();
  for (int b = t; b < NBK; b += BBLK) lcnt[b] = loff[b];
  __syncthreads();
  for (int k = t; k < m; k += BBLK) {
    int d = dst[base + k];
    int b = d >> 8;
    int dl = d & 255;
    int pos = atomicAdd(&lcnt[b], 1);
    sorted[pos] = (unsigned)src[base + k] | ((unsigned)dl << 18);
    bkt16[pos] = (unsigned short)b;
  }
  __syncthreads();
  for (int i = t; i < m; i += BBLK) {
    int b = bkt16[i];
    binned[lbase[b] + (i - loff[b])] = sorted[i];
  }
}

// fused: per-bucket degree (dual LDS counters, 512 thr) -> dinv -> hs1 = fp16((x@W1)*dinv)
__global__ void __launch_bounds__(DBLK) k_ldeg_t1(const unsigned* __restrict__ binned,
                                                  const int* __restrict__ gbase,
                                                  const float* __restrict__ x,
                                                  const float* __restrict__ W1,
                                                  float* __restrict__ dinv,
                                                  __half* __restrict__ hs1, int n) {
  __shared__ int cnt[2][BW];
  __shared__ float w[160];
  int t = threadIdx.x;
  cnt[t >> 8][t & 255] = 0;
  if (t < 160) w[t] = W1[t];
  __syncthreads();
  int b = blockIdx.x;
  int p0 = gbase[b], p1 = gbase[b + 1];
  int h = t >> 8;
  for (int p = p0 + t; p < p1; p += DBLK) atomicAdd(&cnt[h][binned[p] >> 18], 1);
  __syncthreads();
  if (t >= BW) return;
  int v = b * BW + t;
  if (v >= n) return;
  float di = rsqrtf((float)(cnt[0][t] + cnt[1][t]) + 1.0f);
  dinv[v] = di;
  float xi[10];
#pragma unroll
  for (int k = 0; k < 10; k++) xi[k] = x[(size_t)v * 10 + k];
  __half2 hv[8];
#pragma unroll
  for (int j = 0; j < 8; j++) {
    float acc0 = 0.f, acc1 = 0.f;
#pragma unroll
    for (int k = 0; k < 10; k++) {
      acc0 = fmaf(xi[k], w[k * 16 + 2 * j], acc0);
      acc1 = fmaf(xi[k], w[k * 16 + 2 * j + 1], acc1);
    }
    hv[j] = __floats2half2_rn(acc0 * di, acc1 * di);
  }
  float4* o = (float4*)(hs1 + (size_t)v * 16);
  o[0] = *(float4*)&hv[0];
  o[1] = *(float4*)&hv[4];
}

// layer-1 aggregation, zero float atomics: counting-sort by dl in LDS, lane-pair register
// accumulate, fused layer-2 epilogue.
__global__ void __launch_bounds__(ABLK) k_agg1s(const unsigned* __restrict__ binned,
                                                const int* __restrict__ gbase,
                                                const __half* __restrict__ hs1,
                                                const float* __restrict__ dinv,
                                                const float* __restrict__ b1,
                                                const float* __restrict__ W2,
                                                float* __restrict__ hs2, int n) {
  __shared__ int cnt[BW];
  __shared__ int stmp[BW];
  __shared__ int off[BW + 1];
  __shared__ int cur[BW];
  __shared__ int sorted[CAP];
  __shared__ float w2[32];
  __shared__ float sb1[16];
  int t = threadIdx.x;
  if (t < 32) w2[t] = W2[t];
  if (t >= 32 && t < 48) sb1[t - 32] = b1[t - 32];
  int bkt = blockIdx.x;
  int p0 = gbase[bkt], p1 = gbase[bkt + 1];
  const int j = t >> 1;
  const int c = t & 1;
  float acc[8];
#pragma unroll
  for (int q = 0; q < 8; q++) acc[q] = 0.f;

#define ACCR(R) { const __half2* h2_ = (const __half2*)&R; \
    float2 f0_ = __half22float2(h2_[0]); \
    float2 f1_ = __half22float2(h2_[1]); \
    float2 f2_ = __half22float2(h2_[2]); \
    float2 f3_ = __half22float2(h2_[3]); \
    acc[0] += f0_.x; acc[1] += f0_.y; acc[2] += f1_.x; acc[3] += f1_.y; \
    acc[4] += f2_.x; acc[5] += f2_.y; acc[6] += f3_.x; acc[7] += f3_.y; }

  int p = p0;
  while (p < p1) {
    int m = min(CAP, p1 - p);
    if (t < BW) cnt[t] = 0;
    __syncthreads();
    for (int i = t; i < m; i += ABLK) atomicAdd(&cnt[binned[p + i] >> 18], 1);
    __syncthreads();
    if (t < BW) stmp[t] = cnt[t];
    __syncthreads();
    for (int d = 1; d < BW; d <<= 1) {
      int u = 0;
      if (t < BW && t >= d) u = stmp[t - d];
      __syncthreads();
      if (t < BW) stmp[t] += u;
      __syncthreads();
    }
    if (t < BW) { int ex = stmp[t] - cnt[t]; off[t] = ex; cur[t] = ex; }
    if (t == 0) off[BW] = m;
    __syncthreads();
    for (int i = t; i < m; i += ABLK) {
      unsigned pk = binned[p + i];
      int pos = atomicAdd(&cur[pk >> 18], 1);
      sorted[pos] = (int)(pk & 0x3FFFF);
    }
    __syncthreads();
    int i0 = off[j], i1 = off[j + 1];
    int i = i0;
    for (; i + 3 < i1; i += 4) {
      int s0 = sorted[i + 0];
      int s1 = sorted[i + 1];
      int s2 = sorted[i + 2];
      int s3 = sorted[i + 3];
      float4 r0 = *(const float4*)(hs1 + (size_t)s0 * 16 + c * 8);
      float4 r1 = *(const float4*)(hs1 + (size_t)s1 * 16 + c * 8);
      float4 r2 = *(const float4*)(hs1 + (size_t)s2 * 16 + c * 8);
      float4 r3 = *(const float4*)(hs1 + (size_t)s3 * 16 + c * 8);
      ACCR(r0); ACCR(r1); ACCR(r2); ACCR(r3);
    }
    for (; i < i1; i++) {
      int s = sorted[i];
      float4 r = *(const float4*)(hs1 + (size_t)s * 16 + c * 8);
      ACCR(r);
    }
    __syncthreads();
    p += m;
  }
#undef ACCR

  int v = bkt * BW + j;
  if (v < n) {
    float di = dinv[v];
    float4 sf = *(const float4*)(hs1 + (size_t)v * 16 + c * 8);
    const __half2* sh = (const __half2*)&sf;
    float h0c = 0.f, h1c = 0.f;
#pragma unroll
    for (int q = 0; q < 4; q++) {
      float2 sv = __half22float2(sh[q]);
      int f0 = c * 8 + 2 * q;
      int f1 = f0 + 1;
      float a0 = fmaxf(fmaf(di, acc[2 * q + 0] + sv.x, sb1[f0]), 0.f);
      float a1 = fmaxf(fmaf(di, acc[2 * q + 1] + sv.y, sb1[f1]), 0.f);
      h0c = fmaf(a0, w2[f0 * 2 + 0], fmaf(a1, w2[f1 * 2 + 0], h0c));
      h1c = fmaf(a0, w2[f0 * 2 + 1], fmaf(a1, w2[f1 * 2 + 1], h1c));
    }
    float h0 = h0c + __shfl_xor(h0c, 1);
    float h1 = h1c + __shfl_xor(h1c, 1);
    if (c == 0) {
      hs2[(size_t)v * 2 + 0] = h0 * di;
      hs2[(size_t)v * 2 + 1] = h1 * di;
    }
  }
}

// layer-2 aggregate + output; 512 threads, dual LDS accumulators (pad stride 3)
__global__ void __launch_bounds__(DBLK) k_agg2(const unsigned* __restrict__ binned,
                                               const int* __restrict__ gbase,
                                               const float* __restrict__ hs2,
                                               const float* __restrict__ dinv,
                                               const float* __restrict__ b2,
                                               float* __restrict__ out, int n) {
  __shared__ float agg[2][BW * 3];
  int t = threadIdx.x;
  int h = t >> 8;
  for (int i = t & 255; i < BW * 3; i += 256) agg[h][i] = 0.f;
  __syncthreads();
  int bkt = blockIdx.x;
  int p0 = gbase[bkt], p1 = gbase[bkt + 1];
  int p = p0 + t;
  float* ag = agg[h];
#define ACC2(pk, M) { int dl_ = (pk) >> 18; \
    atomicAdd(&ag[dl_ * 3 + 0], M.x); atomicAdd(&ag[dl_ * 3 + 1], M.y); }
  for (; p + 3 * DBLK < p1; p += 4 * DBLK) {
    unsigned pk0 = binned[p];
    unsigned pk1 = binned[p + DBLK];
    unsigned pk2 = binned[p + 2 * DBLK];
    unsigned pk3 = binned[p + 3 * DBLK];
    float2 m0 = *(const float2*)(hs2 + (size_t)(pk0 & 0x3FFFF) * 2);
    float2 m1 = *(const float2*)(hs2 + (size_t)(pk1 & 0x3FFFF) * 2);
    float2 m2 = *(const float2*)(hs2 + (size_t)(pk2 & 0x3FFFF) * 2);
    float2 m3 = *(const float2*)(hs2 + (size_t)(pk3 & 0x3FFFF) * 2);
    ACC2(pk0, m0); ACC2(pk1, m1); ACC2(pk2, m2); ACC2(pk3, m3);
  }
  for (; p < p1; p += DBLK) {
    unsigned pk = binned[p];
    float2 m = *(const float2*)(hs2 + (size_t)(pk & 0x3FFFF) * 2);
    ACC2(pk, m);
  }
#undef ACC2
  __syncthreads();
  if (t < BW) {
    int v = bkt * BW + t;
    if (v < n) {
      float di = dinv[v];
      float a0 = agg[0][t * 3 + 0] + agg[1][t * 3 + 0];
      float a1 = agg[0][t * 3 + 1] + agg[1][t * 3 + 1];
      out[(size_t)v * 2 + 0] = fmaf(di, a0 + hs2[(size_t)v * 2 + 0], b2[0]);
      out[(size_t)v * 2 + 1] = fmaf(di, a1 + hs2[(size_t)v * 2 + 1], b2[1]);
    }
  }
}

extern "C" void kernel_launch(void* const* d_in, const int* in_sizes, int n_in,
                              void* d_out, int out_size, void* d_ws, size_t ws_size,
                              hipStream_t stream) {
  const float* x  = (const float*)d_in[0];
  const int*   ei = (const int*)d_in[1];
  const float* W1 = (const float*)d_in[2];
  const float* b1 = (const float*)d_in[3];
  const float* W2 = (const float*)d_in[4];
  const float* b2 = (const float*)d_in[5];
  float* out = (float*)d_out;

  const int n = in_sizes[0] / 10;   // 200000
  const int e = in_sizes[1] / 2;    // 6400000
  const int* src = ei;
  const int* dst = ei + e;

  int gC = (e + CHUNK - 1) / CHUNK;   // 1563 binning blocks

  // workspace layout (~39.4 MB)
  char* ws = (char*)d_ws;
  int*      gcnt      = (int*)ws;      ws += (size_t)NBK * 4;
  int*      gbase     = (int*)ws;      ws += ((size_t)NBK + 1) * 4;
  int*      gcur      = (int*)ws;      ws += (size_t)NBK * 4;
  int*      blockhist = (int*)ws;      ws += (size_t)gC * NBK * 4;
  unsigned* binned    = (unsigned*)ws; ws += (size_t)e * 4;
  float*    dinv      = (float*)ws;    ws += (size_t)n * 4;
  __half*   hs1       = (__half*)ws;   ws += (size_t)n * 16 * 2;
  float*    hs2       = (float*)ws;    ws += (size_t)n * 2 * 4;

  k_zero_i<<<(NBK + BLK - 1) / BLK, BLK, 0, stream>>>(gcnt, NBK);
  k_hist<<<gC, BLK, 0, stream>>>(dst, e, gcnt, blockhist);
  k_scan<<<1, 1024, 0, stream>>>(gcnt, gbase, gcur, e);
  k_bin<<<gC, BBLK, 0, stream>>>(src, dst, e, gcur, blockhist, binned);
  k_ldeg_t1<<<NBK, DBLK, 0, stream>>>(binned, gbase, x, W1, dinv, hs1, n);
  k_agg1s<<<NBK, ABLK, 0, stream>>>(binned, gbase, hs1, dinv, b1, W2, hs2, n);
  k_agg2<<<NBK, DBLK, 0, stream>>>(binned, gbase, hs2, dinv, b2, out, n);
}

// Round 14
// 366.983 us; speedup vs baseline: 1.0663x; 1.0663x over previous
//
#include <hip/hip_runtime.h>
#include <hip/hip_fp16.h>

#define BLK 256
#define BBLK 512             // k_bin block
#define ABLK 512             // agg1 block: 256 lane-pairs
#define DBLK 512             // ldeg_t1 / agg2 block (dual LDS accumulators)
#define NBK 782              // dst buckets of 256 nodes (782*256 >= 200000)
#define BW 256               // nodes per bucket (dl fits 8 bits)
#define CAP 9984             // edges counting-sorted per chunk in agg1 (1 chunk for avg bucket)
#define CHUNK 6144           // edges per binning block -> 1042 blocks

// ---------- bucket build ----------

__global__ void k_zero_i(int* __restrict__ p, int n) {
  int i = blockIdx.x * blockDim.x + threadIdx.x;
  if (i < n) p[i] = 0;
}

// per-block histogram -> blockhist row (persisted) + global bucket counts
__global__ void k_hist(const int* __restrict__ dst, int e, int* __restrict__ gcnt,
                       int* __restrict__ blockhist) {
  __shared__ int h[NBK];
  for (int i = threadIdx.x; i < NBK; i += BLK) h[i] = 0;
  __syncthreads();
  int base = blockIdx.x * CHUNK;
  int m = min(CHUNK, e - base);
  for (int k = threadIdx.x; k < m; k += BLK) atomicAdd(&h[dst[base + k] >> 8], 1);
  __syncthreads();
  int* row = blockhist + (size_t)blockIdx.x * NBK;
  for (int b = threadIdx.x; b < NBK; b += BLK) {
    int c = h[b];
    row[b] = c;
    if (c) atomicAdd(&gcnt[b], c);
  }
}

// exclusive scan of gcnt[NBK] -> gbase[NBK+1]; init gcur. single block, 1024 thr.
__global__ void k_scan(const int* __restrict__ gcnt, int* __restrict__ gbase,
                       int* __restrict__ gcur, int e) {
  __shared__ int s[1024];
  int t = threadIdx.x;
  int v = (t < NBK) ? gcnt[t] : 0;
  s[t] = v;
  __syncthreads();
  for (int d = 1; d < 1024; d <<= 1) {
    int u = (t >= d) ? s[t - d] : 0;
    __syncthreads();
    s[t] += u;
    __syncthreads();
  }
  if (t < NBK) { int ex = s[t] - v; gbase[t] = ex; gcur[t] = ex; }
  if (t == 0) gbase[NBK] = e;
}

// bin edges: load saved histogram, LDS counting-sort, coalesced write-out with
// direct pos->bucket lookup.
__global__ void __launch_bounds__(BBLK) k_bin(const int* __restrict__ src,
                                              const int* __restrict__ dst, int e,
                                              int* __restrict__ gcur,
                                              const int* __restrict__ blockhist,
                                              unsigned* __restrict__ binned) {
  __shared__ int lcnt[NBK];        // histogram, then reused as scatter cursor
  __shared__ int loff[NBK + 1];
  __shared__ int lbase[NBK];
  __shared__ int part[BBLK];
  __shared__ unsigned sorted[CHUNK];        // 24 KB
  __shared__ unsigned short bkt16[CHUNK];   // 12 KB
  int t = threadIdx.x;
  int base = blockIdx.x * CHUNK;
  int m = min(CHUNK, e - base);

  const int* row = blockhist + (size_t)blockIdx.x * NBK;
  for (int i = t; i < NBK; i += BBLK) lcnt[i] = row[i];
  __syncthreads();
  // exclusive scan over 782 bins (2 bins/thread + Hillis-Steele over 512 partials)
  int b0 = 2 * t;
  int s0 = (b0 + 0 < NBK) ? lcnt[b0 + 0] : 0;
  int s1 = (b0 + 1 < NBK) ? lcnt[b0 + 1] : 0;
  int tsum = s0 + s1;
  part[t] = tsum;
  __syncthreads();
  for (int d = 1; d < BBLK; d <<= 1) {
    int u = (t >= d) ? part[t - d] : 0;
    __syncthreads();
    part[t] += u;
    __syncthreads();
  }
  int ex = part[t] - tsum;
  if (b0 + 0 < NBK) loff[b0 + 0] = ex;
  if (b0 + 1 < NBK) loff[b0 + 1] = ex + s0;
  if (t == 0) loff[NBK] = m;
  __syncthreads();
  for (int b = t; b < NBK; b += BBLK) {
    int c = lcnt[b];
    lbase[b] = c ? atomicAdd(&gcur[b], c) : 0;
  }
  __syncthreads();
  for (int b = t; b < NBK; b += BBLK) lcnt[b] = loff[b];
  __syncthreads();
  for (int k = t; k < m; k += BBLK) {
    int d = dst[base + k];
    int b = d >> 8;
    int dl = d & 255;
    int pos = atomicAdd(&lcnt[b], 1);
    sorted[pos] = (unsigned)src[base + k] | ((unsigned)dl << 18);
    bkt16[pos] = (unsigned short)b;
  }
  __syncthreads();
  for (int i = t; i < m; i += BBLK) {
    int b = bkt16[i];
    binned[lbase[b] + (i - loff[b])] = sorted[i];
  }
}

// fused: per-bucket degree (dual LDS counters, 512 thr) -> dinv -> hs1 = fp16((x@W1)*dinv)
__global__ void __launch_bounds__(DBLK) k_ldeg_t1(const unsigned* __restrict__ binned,
                                                  const int* __restrict__ gbase,
                                                  const float* __restrict__ x,
                                                  const float* __restrict__ W1,
                                                  float* __restrict__ dinv,
                                                  __half* __restrict__ hs1, int n) {
  __shared__ int cnt[2][BW];
  __shared__ float w[160];
  int t = threadIdx.x;
  cnt[t >> 8][t & 255] = 0;
  if (t < 160) w[t] = W1[t];
  __syncthreads();
  int b = blockIdx.x;
  int p0 = gbase[b], p1 = gbase[b + 1];
  int h = t >> 8;
  for (int p = p0 + t; p < p1; p += DBLK) atomicAdd(&cnt[h][binned[p] >> 18], 1);
  __syncthreads();
  if (t >= BW) return;
  int v = b * BW + t;
  if (v >= n) return;
  float di = rsqrtf((float)(cnt[0][t] + cnt[1][t]) + 1.0f);
  dinv[v] = di;
  float xi[10];
#pragma unroll
  for (int k = 0; k < 10; k++) xi[k] = x[(size_t)v * 10 + k];
  __half2 hv[8];
#pragma unroll
  for (int j = 0; j < 8; j++) {
    float acc0 = 0.f, acc1 = 0.f;
#pragma unroll
    for (int k = 0; k < 10; k++) {
      acc0 = fmaf(xi[k], w[k * 16 + 2 * j], acc0);
      acc1 = fmaf(xi[k], w[k * 16 + 2 * j + 1], acc1);
    }
    hv[j] = __floats2half2_rn(acc0 * di, acc1 * di);
  }
  float4* o = (float4*)(hs1 + (size_t)v * 16);
  o[0] = *(float4*)&hv[0];
  o[1] = *(float4*)&hv[4];
}

// layer-1 aggregation, zero float atomics: counting-sort by dl in LDS, lane-pair register
// accumulate, fused layer-2 epilogue.
__global__ void __launch_bounds__(ABLK) k_agg1s(const unsigned* __restrict__ binned,
                                                const int* __restrict__ gbase,
                                                const __half* __restrict__ hs1,
                                                const float* __restrict__ dinv,
                                                const float* __restrict__ b1,
                                                const float* __restrict__ W2,
                                                float* __restrict__ hs2, int n) {
  __shared__ int cnt[BW];
  __shared__ int stmp[BW];
  __shared__ int off[BW + 1];
  __shared__ int cur[BW];
  __shared__ int sorted[CAP];
  __shared__ float w2[32];
  __shared__ float sb1[16];
  int t = threadIdx.x;
  if (t < 32) w2[t] = W2[t];
  if (t >= 32 && t < 48) sb1[t - 32] = b1[t - 32];
  int bkt = blockIdx.x;
  int p0 = gbase[bkt], p1 = gbase[bkt + 1];
  const int j = t >> 1;
  const int c = t & 1;
  float acc[8];
#pragma unroll
  for (int q = 0; q < 8; q++) acc[q] = 0.f;

#define ACCR(R) { const __half2* h2_ = (const __half2*)&R; \
    float2 f0_ = __half22float2(h2_[0]); \
    float2 f1_ = __half22float2(h2_[1]); \
    float2 f2_ = __half22float2(h2_[2]); \
    float2 f3_ = __half22float2(h2_[3]); \
    acc[0] += f0_.x; acc[1] += f0_.y; acc[2] += f1_.x; acc[3] += f1_.y; \
    acc[4] += f2_.x; acc[5] += f2_.y; acc[6] += f3_.x; acc[7] += f3_.y; }

  int p = p0;
  while (p < p1) {
    int m = min(CAP, p1 - p);
    if (t < BW) cnt[t] = 0;
    __syncthreads();
    for (int i = t; i < m; i += ABLK) atomicAdd(&cnt[binned[p + i] >> 18], 1);
    __syncthreads();
    if (t < BW) stmp[t] = cnt[t];
    __syncthreads();
    for (int d = 1; d < BW; d <<= 1) {
      int u = 0;
      if (t < BW && t >= d) u = stmp[t - d];
      __syncthreads();
      if (t < BW) stmp[t] += u;
      __syncthreads();
    }
    if (t < BW) { int ex = stmp[t] - cnt[t]; off[t] = ex; cur[t] = ex; }
    if (t == 0) off[BW] = m;
    __syncthreads();
    for (int i = t; i < m; i += ABLK) {
      unsigned pk = binned[p + i];
      int pos = atomicAdd(&cur[pk >> 18], 1);
      sorted[pos] = (int)(pk & 0x3FFFF);
    }
    __syncthreads();
    int i0 = off[j], i1 = off[j + 1];
    int i = i0;
    for (; i + 3 < i1; i += 4) {
      int s0 = sorted[i + 0];
      int s1 = sorted[i + 1];
      int s2 = sorted[i + 2];
      int s3 = sorted[i + 3];
      float4 r0 = *(const float4*)(hs1 + (size_t)s0 * 16 + c * 8);
      float4 r1 = *(const float4*)(hs1 + (size_t)s1 * 16 + c * 8);
      float4 r2 = *(const float4*)(hs1 + (size_t)s2 * 16 + c * 8);
      float4 r3 = *(const float4*)(hs1 + (size_t)s3 * 16 + c * 8);
      ACCR(r0); ACCR(r1); ACCR(r2); ACCR(r3);
    }
    for (; i < i1; i++) {
      int s = sorted[i];
      float4 r = *(const float4*)(hs1 + (size_t)s * 16 + c * 8);
      ACCR(r);
    }
    __syncthreads();
    p += m;
  }
#undef ACCR

  int v = bkt * BW + j;
  if (v < n) {
    float di = dinv[v];
    float4 sf = *(const float4*)(hs1 + (size_t)v * 16 + c * 8);
    const __half2* sh = (const __half2*)&sf;
    float h0c = 0.f, h1c = 0.f;
#pragma unroll
    for (int q = 0; q < 4; q++) {
      float2 sv = __half22float2(sh[q]);
      int f0 = c * 8 + 2 * q;
      int f1 = f0 + 1;
      float a0 = fmaxf(fmaf(di, acc[2 * q + 0] + sv.x, sb1[f0]), 0.f);
      float a1 = fmaxf(fmaf(di, acc[2 * q + 1] + sv.y, sb1[f1]), 0.f);
      h0c = fmaf(a0, w2[f0 * 2 + 0], fmaf(a1, w2[f1 * 2 + 0], h0c));
      h1c = fmaf(a0, w2[f0 * 2 + 1], fmaf(a1, w2[f1 * 2 + 1], h1c));
    }
    float h0 = h0c + __shfl_xor(h0c, 1);
    float h1 = h1c + __shfl_xor(h1c, 1);
    if (c == 0) {
      hs2[(size_t)v * 2 + 0] = h0 * di;
      hs2[(size_t)v * 2 + 1] = h1 * di;
    }
  }
}

// layer-2 aggregate + output; 512 threads, dual LDS accumulators (pad stride 3)
__global__ void __launch_bounds__(DBLK) k_agg2(const unsigned* __restrict__ binned,
                                               const int* __restrict__ gbase,
                                               const float* __restrict__ hs2,
                                               const float* __restrict__ dinv,
                                               const float* __restrict__ b2,
                                               float* __restrict__ out, int n) {
  __shared__ float agg[2][BW * 3];
  int t = threadIdx.x;
  int h = t >> 8;
  for (int i = t & 255; i < BW * 3; i += 256) agg[h][i] = 0.f;
  __syncthreads();
  int bkt = blockIdx.x;
  int p0 = gbase[bkt], p1 = gbase[bkt + 1];
  int p = p0 + t;
  float* ag = agg[h];
#define ACC2(pk, M) { int dl_ = (pk) >> 18; \
    atomicAdd(&ag[dl_ * 3 + 0], M.x); atomicAdd(&ag[dl_ * 3 + 1], M.y); }
  for (; p + 3 * DBLK < p1; p += 4 * DBLK) {
    unsigned pk0 = binned[p];
    unsigned pk1 = binned[p + DBLK];
    unsigned pk2 = binned[p + 2 * DBLK];
    unsigned pk3 = binned[p + 3 * DBLK];
    float2 m0 = *(const float2*)(hs2 + (size_t)(pk0 & 0x3FFFF) * 2);
    float2 m1 = *(const float2*)(hs2 + (size_t)(pk1 & 0x3FFFF) * 2);
    float2 m2 = *(const float2*)(hs2 + (size_t)(pk2 & 0x3FFFF) * 2);
    float2 m3 = *(const float2*)(hs2 + (size_t)(pk3 & 0x3FFFF) * 2);
    ACC2(pk0, m0); ACC2(pk1, m1); ACC2(pk2, m2); ACC2(pk3, m3);
  }
  for (; p < p1; p += DBLK) {
    unsigned pk = binned[p];
    float2 m = *(const float2*)(hs2 + (size_t)(pk & 0x3FFFF) * 2);
    ACC2(pk, m);
  }
#undef ACC2
  __syncthreads();
  if (t < BW) {
    int v = bkt * BW + t;
    if (v < n) {
      float di = dinv[v];
      float a0 = agg[0][t * 3 + 0] + agg[1][t * 3 + 0];
      float a1 = agg[0][t * 3 + 1] + agg[1][t * 3 + 1];
      out[(size_t)v * 2 + 0] = fmaf(di, a0 + hs2[(size_t)v * 2 + 0], b2[0]);
      out[(size_t)v * 2 + 1] = fmaf(di, a1 + hs2[(size_t)v * 2 + 1], b2[1]);
    }
  }
}

extern "C" void kernel_launch(void* const* d_in, const int* in_sizes, int n_in,
                              void* d_out, int out_size, void* d_ws, size_t ws_size,
                              hipStream_t stream) {
  const float* x  = (const float*)d_in[0];
  const int*   ei = (const int*)d_in[1];
  const float* W1 = (const float*)d_in[2];
  const float* b1 = (const float*)d_in[3];
  const float* W2 = (const float*)d_in[4];
  const float* b2 = (const float*)d_in[5];
  float* out = (float*)d_out;

  const int n = in_sizes[0] / 10;   // 200000
  const int e = in_sizes[1] / 2;    // 6400000
  const int* src = ei;
  const int* dst = ei + e;

  int gC = (e + CHUNK - 1) / CHUNK;   // 1042 binning blocks

  // workspace layout (~38 MB)
  char* ws = (char*)d_ws;
  int*      gcnt      = (int*)ws;      ws += (size_t)NBK * 4;
  int*      gbase     = (int*)ws;      ws += ((size_t)NBK + 1) * 4;
  int*      gcur      = (int*)ws;      ws += (size_t)NBK * 4;
  int*      blockhist = (int*)ws;      ws += (size_t)gC * NBK * 4;
  unsigned* binned    = (unsigned*)ws; ws += (size_t)e * 4;
  float*    dinv      = (float*)ws;    ws += (size_t)n * 4;
  __half*   hs1       = (__half*)ws;   ws += (size_t)n * 16 * 2;
  float*    hs2       = (float*)ws;    ws += (size_t)n * 2 * 4;

  k_zero_i<<<(NBK + BLK - 1) / BLK, BLK, 0, stream>>>(gcnt, NBK);
  k_hist<<<gC, BLK, 0, stream>>>(dst, e, gcnt, blockhist);
  k_scan<<<1, 1024, 0, stream>>>(gcnt, gbase, gcur, e);
  k_bin<<<gC, BBLK, 0, stream>>>(src, dst, e, gcur, blockhist, binned);
  k_ldeg_t1<<<NBK, DBLK, 0, stream>>>(binned, gbase, x, W1, dinv, hs1, n);
  k_agg1s<<<NBK, ABLK, 0, stream>>>(binned, gbase, hs1, dinv, b1, W2, hs2, n);
  k_agg2<<<NBK, DBLK, 0, stream>>>(binned, gbase, hs2, dinv, b2, out, n);
}

// Round 15
// 349.054 us; speedup vs baseline: 1.1210x; 1.0514x over previous
//
#include <hip/hip_runtime.h>
#include <hip/hip_fp16.h>

#define BLK 256
#define BBLK 512             // k_bin block
#define ABLK 512             // agg1 block: 256 lane-pairs
#define DBLK 512             // ldeg_t1 block (dual LDS counters)
#define NBK 782              // dst buckets of 256 nodes (782*256 >= 200000)
#define BW 256               // nodes per bucket (dl fits 8 bits)
#define CAP 9984             // edges sorted per chunk in agg1 (avg bucket 8184 -> 1 chunk)
#define NCH 3                // max chunks per bucket tracked in doff (8184+20sigma << 2*CAP)
#define CHUNK 6144           // edges per binning block -> 1042 blocks

// ---------- bucket build ----------

// per-block histogram -> blockhist row (persisted) + global bucket counts
__global__ void k_hist(const int* __restrict__ dst, int e, int* __restrict__ gcnt,
                       int* __restrict__ blockhist) {
  __shared__ int h[NBK];
  for (int i = threadIdx.x; i < NBK; i += BLK) h[i] = 0;
  __syncthreads();
  int base = blockIdx.x * CHUNK;
  int m = min(CHUNK, e - base);
  for (int k = threadIdx.x; k < m; k += BLK) atomicAdd(&h[dst[base + k] >> 8], 1);
  __syncthreads();
  int* row = blockhist + (size_t)blockIdx.x * NBK;
  for (int b = threadIdx.x; b < NBK; b += BLK) {
    int c = h[b];
    row[b] = c;
    if (c) atomicAdd(&gcnt[b], c);
  }
}

// exclusive scan of gcnt[NBK] -> gbase[NBK+1]; init gcur. single block, 1024 thr.
__global__ void k_scan(const int* __restrict__ gcnt, int* __restrict__ gbase,
                       int* __restrict__ gcur, int e) {
  __shared__ int s[1024];
  int t = threadIdx.x;
  int v = (t < NBK) ? gcnt[t] : 0;
  s[t] = v;
  __syncthreads();
  for (int d = 1; d < 1024; d <<= 1) {
    int u = (t >= d) ? s[t - d] : 0;
    __syncthreads();
    s[t] += u;
    __syncthreads();
  }
  if (t < NBK) { int ex = s[t] - v; gbase[t] = ex; gcur[t] = ex; }
  if (t == 0) gbase[NBK] = e;
}

// bin edges: load saved histogram, LDS counting-sort, coalesced write-out with
// direct pos->bucket lookup.
__global__ void __launch_bounds__(BBLK) k_bin(const int* __restrict__ src,
                                              const int* __restrict__ dst, int e,
                                              int* __restrict__ gcur,
                                              const int* __restrict__ blockhist,
                                              unsigned* __restrict__ binned) {
  __shared__ int lcnt[NBK];        // histogram, then reused as scatter cursor
  __shared__ int loff[NBK + 1];
  __shared__ int lbase[NBK];
  __shared__ int part[BBLK];
  __shared__ unsigned sorted[CHUNK];        // 24 KB
  __shared__ unsigned short bkt16[CHUNK];   // 12 KB
  int t = threadIdx.x;
  int base = blockIdx.x * CHUNK;
  int m = min(CHUNK, e - base);

  const int* row = blockhist + (size_t)blockIdx.x * NBK;
  for (int i = t; i < NBK; i += BBLK) lcnt[i] = row[i];
  __syncthreads();
  int b0 = 2 * t;
  int s0 = (b0 + 0 < NBK) ? lcnt[b0 + 0] : 0;
  int s1 = (b0 + 1 < NBK) ? lcnt[b0 + 1] : 0;
  int tsum = s0 + s1;
  part[t] = tsum;
  __syncthreads();
  for (int d = 1; d < BBLK; d <<= 1) {
    int u = (t >= d) ? part[t - d] : 0;
    __syncthreads();
    part[t] += u;
    __syncthreads();
  }
  int ex = part[t] - tsum;
  if (b0 + 0 < NBK) loff[b0 + 0] = ex;
  if (b0 + 1 < NBK) loff[b0 + 1] = ex + s0;
  if (t == 0) loff[NBK] = m;
  __syncthreads();
  for (int b = t; b < NBK; b += BBLK) {
    int c = lcnt[b];
    lbase[b] = c ? atomicAdd(&gcur[b], c) : 0;
  }
  __syncthreads();
  for (int b = t; b < NBK; b += BBLK) lcnt[b] = loff[b];
  __syncthreads();
  for (int k = t; k < m; k += BBLK) {
    int d = dst[base + k];
    int b = d >> 8;
    int dl = d & 255;
    int pos = atomicAdd(&lcnt[b], 1);
    sorted[pos] = (unsigned)src[base + k] | ((unsigned)dl << 18);
    bkt16[pos] = (unsigned short)b;
  }
  __syncthreads();
  for (int i = t; i < m; i += BBLK) {
    int b = bkt16[i];
    binned[lbase[b] + (i - loff[b])] = sorted[i];
  }
}

// fused: per-bucket degree (dual LDS counters, 512 thr) -> dinv -> hs1 = fp16((x@W1)*dinv)
__global__ void __launch_bounds__(DBLK) k_ldeg_t1(const unsigned* __restrict__ binned,
                                                  const int* __restrict__ gbase,
                                                  const float* __restrict__ x,
                                                  const float* __restrict__ W1,
                                                  float* __restrict__ dinv,
                                                  __half* __restrict__ hs1, int n) {
  __shared__ int cnt[2][BW];
  __shared__ float w[160];
  int t = threadIdx.x;
  cnt[t >> 8][t & 255] = 0;
  if (t < 160) w[t] = W1[t];
  __syncthreads();
  int b = blockIdx.x;
  int p0 = gbase[b], p1 = gbase[b + 1];
  int h = t >> 8;
  for (int p = p0 + t; p < p1; p += DBLK) atomicAdd(&cnt[h][binned[p] >> 18], 1);
  __syncthreads();
  if (t >= BW) return;
  int v = b * BW + t;
  if (v >= n) return;
  float di = rsqrtf((float)(cnt[0][t] + cnt[1][t]) + 1.0f);
  dinv[v] = di;
  float xi[10];
#pragma unroll
  for (int k = 0; k < 10; k++) xi[k] = x[(size_t)v * 10 + k];
  __half2 hv[8];
#pragma unroll
  for (int j = 0; j < 8; j++) {
    float acc0 = 0.f, acc1 = 0.f;
#pragma unroll
    for (int k = 0; k < 10; k++) {
      acc0 = fmaf(xi[k], w[k * 16 + 2 * j], acc0);
      acc1 = fmaf(xi[k], w[k * 16 + 2 * j + 1], acc1);
    }
    hv[j] = __floats2half2_rn(acc0 * di, acc1 * di);
  }
  float4* o = (float4*)(hs1 + (size_t)v * 16);
  o[0] = *(float4*)&hv[0];
  o[1] = *(float4*)&hv[4];
}

// layer-1 aggregation: counting-sort by dl in LDS, lane-pair register accumulate,
// fused layer-2 epilogue. NEW: persists the dl-sorted edges (src-only) back into
// binned in-place + per-chunk offset tables to doff, for atomic-free k_agg2.
__global__ void __launch_bounds__(ABLK) k_agg1s(unsigned* __restrict__ binned,
                                                const int* __restrict__ gbase,
                                                int* __restrict__ doff,
                                                const __half* __restrict__ hs1,
                                                const float* __restrict__ dinv,
                                                const float* __restrict__ b1,
                                                const float* __restrict__ W2,
                                                float* __restrict__ hs2, int n) {
  __shared__ int cnt[BW];
  __shared__ int stmp[BW];
  __shared__ int off[BW + 1];
  __shared__ int cur[BW];
  __shared__ int sorted[CAP];
  __shared__ float w2[32];
  __shared__ float sb1[16];
  int t = threadIdx.x;
  if (t < 32) w2[t] = W2[t];
  if (t >= 32 && t < 48) sb1[t - 32] = b1[t - 32];
  int bkt = blockIdx.x;
  int p0 = gbase[bkt], p1 = gbase[bkt + 1];
  const int j = t >> 1;
  const int c = t & 1;
  float acc[8];
#pragma unroll
  for (int q = 0; q < 8; q++) acc[q] = 0.f;

#define ACCR(R) { const __half2* h2_ = (const __half2*)&R; \
    float2 f0_ = __half22float2(h2_[0]); \
    float2 f1_ = __half22float2(h2_[1]); \
    float2 f2_ = __half22float2(h2_[2]); \
    float2 f3_ = __half22float2(h2_[3]); \
    acc[0] += f0_.x; acc[1] += f0_.y; acc[2] += f1_.x; acc[3] += f1_.y; \
    acc[4] += f2_.x; acc[5] += f2_.y; acc[6] += f3_.x; acc[7] += f3_.y; }

  int p = p0;
  int cidx = 0;
  while (p < p1) {
    int m = min(CAP, p1 - p);
    if (t < BW) cnt[t] = 0;
    __syncthreads();
    for (int i = t; i < m; i += ABLK) atomicAdd(&cnt[binned[p + i] >> 18], 1);
    __syncthreads();
    if (t < BW) stmp[t] = cnt[t];
    __syncthreads();
    for (int d = 1; d < BW; d <<= 1) {
      int u = 0;
      if (t < BW && t >= d) u = stmp[t - d];
      __syncthreads();
      if (t < BW) stmp[t] += u;
      __syncthreads();
    }
    if (t < BW) { int ex = stmp[t] - cnt[t]; off[t] = ex; cur[t] = ex; }
    if (t == 0) off[BW] = m;
    __syncthreads();
    for (int i = t; i < m; i += ABLK) {
      unsigned pk = binned[p + i];
      int pos = atomicAdd(&cur[pk >> 18], 1);
      sorted[pos] = (int)(pk & 0x3FFFF);
    }
    __syncthreads();
    // persist: dl-sorted srcs back into binned (in-place) + offset table
    for (int i = t; i < m; i += ABLK) binned[p + i] = (unsigned)sorted[i];
    if (cidx < NCH && t <= BW) doff[((size_t)bkt * NCH + cidx) * (BW + 1) + t] = off[t];
    // register gather over this dst's sorted segment
    int i0 = off[j], i1 = off[j + 1];
    int i = i0;
    for (; i + 3 < i1; i += 4) {
      int s0 = sorted[i + 0];
      int s1 = sorted[i + 1];
      int s2 = sorted[i + 2];
      int s3 = sorted[i + 3];
      float4 r0 = *(const float4*)(hs1 + (size_t)s0 * 16 + c * 8);
      float4 r1 = *(const float4*)(hs1 + (size_t)s1 * 16 + c * 8);
      float4 r2 = *(const float4*)(hs1 + (size_t)s2 * 16 + c * 8);
      float4 r3 = *(const float4*)(hs1 + (size_t)s3 * 16 + c * 8);
      ACCR(r0); ACCR(r1); ACCR(r2); ACCR(r3);
    }
    for (; i < i1; i++) {
      int s = sorted[i];
      float4 r = *(const float4*)(hs1 + (size_t)s * 16 + c * 8);
      ACCR(r);
    }
    __syncthreads();
    p += m;
    cidx++;
  }
#undef ACCR

  int v = bkt * BW + j;
  if (v < n) {
    float di = dinv[v];
    float4 sf = *(const float4*)(hs1 + (size_t)v * 16 + c * 8);
    const __half2* sh = (const __half2*)&sf;
    float h0c = 0.f, h1c = 0.f;
#pragma unroll
    for (int q = 0; q < 4; q++) {
      float2 sv = __half22float2(sh[q]);
      int f0 = c * 8 + 2 * q;
      int f1 = f0 + 1;
      float a0 = fmaxf(fmaf(di, acc[2 * q + 0] + sv.x, sb1[f0]), 0.f);
      float a1 = fmaxf(fmaf(di, acc[2 * q + 1] + sv.y, sb1[f1]), 0.f);
      h0c = fmaf(a0, w2[f0 * 2 + 0], fmaf(a1, w2[f1 * 2 + 0], h0c));
      h1c = fmaf(a0, w2[f0 * 2 + 1], fmaf(a1, w2[f1 * 2 + 1], h1c));
    }
    float h0 = h0c + __shfl_xor(h0c, 1);
    float h1 = h1c + __shfl_xor(h1c, 1);
    if (c == 0) {
      hs2[(size_t)v * 2 + 0] = h0 * di;
      hs2[(size_t)v * 2 + 1] = h1 * di;
    }
  }
}

// layer-2 aggregate + output: ZERO atomics. Thread j owns dst j; reads its
// contiguous dl-sorted segment per chunk (via doff), register-accumulates.
__global__ void __launch_bounds__(BLK) k_agg2(const unsigned* __restrict__ binned,
                                              const int* __restrict__ gbase,
                                              const int* __restrict__ doff,
                                              const float* __restrict__ hs2,
                                              const float* __restrict__ dinv,
                                              const float* __restrict__ b2,
                                              float* __restrict__ out, int n) {
  int t = threadIdx.x;            // one thread per dst-local
  int bkt = blockIdx.x;
  int p0 = gbase[bkt], p1 = gbase[bkt + 1];
  float a0 = 0.f, a1 = 0.f;
  int cidx = 0;
  for (int p = p0; p < p1; p += CAP, cidx++) {
    const int* row = doff + ((size_t)bkt * NCH + cidx) * (BW + 1);
    int i0 = row[t], i1 = row[t + 1];
    const unsigned* bp = binned + p;
    int i = i0;
    for (; i + 3 < i1; i += 4) {
      int s0 = bp[i + 0];
      int s1 = bp[i + 1];
      int s2 = bp[i + 2];
      int s3 = bp[i + 3];
      float2 m0 = *(const float2*)(hs2 + (size_t)s0 * 2);
      float2 m1 = *(const float2*)(hs2 + (size_t)s1 * 2);
      float2 m2 = *(const float2*)(hs2 + (size_t)s2 * 2);
      float2 m3 = *(const float2*)(hs2 + (size_t)s3 * 2);
      a0 += m0.x + m1.x + m2.x + m3.x;
      a1 += m0.y + m1.y + m2.y + m3.y;
    }
    for (; i < i1; i++) {
      float2 m = *(const float2*)(hs2 + (size_t)bp[i] * 2);
      a0 += m.x;
      a1 += m.y;
    }
  }
  int v = bkt * BW + t;
  if (v < n) {
    float di = dinv[v];
    out[(size_t)v * 2 + 0] = fmaf(di, a0 + hs2[(size_t)v * 2 + 0], b2[0]);
    out[(size_t)v * 2 + 1] = fmaf(di, a1 + hs2[(size_t)v * 2 + 1], b2[1]);
  }
}

extern "C" void kernel_launch(void* const* d_in, const int* in_sizes, int n_in,
                              void* d_out, int out_size, void* d_ws, size_t ws_size,
                              hipStream_t stream) {
  const float* x  = (const float*)d_in[0];
  const int*   ei = (const int*)d_in[1];
  const float* W1 = (const float*)d_in[2];
  const float* b1 = (const float*)d_in[3];
  const float* W2 = (const float*)d_in[4];
  const float* b2 = (const float*)d_in[5];
  float* out = (float*)d_out;

  const int n = in_sizes[0] / 10;   // 200000
  const int e = in_sizes[1] / 2;    // 6400000
  const int* src = ei;
  const int* dst = ei + e;

  int gC = (e + CHUNK - 1) / CHUNK;   // 1042 binning blocks

  // workspace layout (~40.4 MB)
  char* ws = (char*)d_ws;
  int*      gcnt      = (int*)ws;      ws += (size_t)NBK * 4;
  int*      gbase     = (int*)ws;      ws += ((size_t)NBK + 1) * 4;
  int*      gcur      = (int*)ws;      ws += (size_t)NBK * 4;
  int*      doff      = (int*)ws;      ws += (size_t)NBK * NCH * (BW + 1) * 4;
  int*      blockhist = (int*)ws;      ws += (size_t)gC * NBK * 4;
  unsigned* binned    = (unsigned*)ws; ws += (size_t)e * 4;
  float*    dinv      = (float*)ws;    ws += (size_t)n * 4;
  __half*   hs1       = (__half*)ws;   ws += (size_t)n * 16 * 2;
  float*    hs2       = (float*)ws;    ws += (size_t)n * 2 * 4;

  hipMemsetAsync(gcnt, 0, (size_t)NBK * 4, stream);
  k_hist<<<gC, BLK, 0, stream>>>(dst, e, gcnt, blockhist);
  k_scan<<<1, 1024, 0, stream>>>(gcnt, gbase, gcur, e);
  k_bin<<<gC, BBLK, 0, stream>>>(src, dst, e, gcur, blockhist, binned);
  k_ldeg_t1<<<NBK, DBLK, 0, stream>>>(binned, gbase, x, W1, dinv, hs1, n);
  k_agg1s<<<NBK, ABLK, 0, stream>>>(binned, gbase, doff, hs1, dinv, b1, W2, hs2, n);
  k_agg2<<<NBK, BLK, 0, stream>>>(binned, gbase, doff, hs2, dinv, b2, out, n);
}